// Round 23
// baseline (476.984 us; speedup 1.0000x reference)
//
#include <hip/hip_runtime.h>
#include <hip/hip_cooperative_groups.h>

namespace cg = cooperative_groups;

#define NB 512
#define NS 47
#define NP 48
#define DIM 32
#define NFF 2048
#define NHID 256
#define FTOK 48

#define VSTR 520
#define PSTR 72

typedef _Float16 f16x8 __attribute__((ext_vector_type(8)));
typedef _Float16 f16x4 __attribute__((ext_vector_type(4)));
typedef float f32x4 __attribute__((ext_vector_type(4)));

__constant__ float POSC[NS * 3] = {
  0,3,0.5f, 0,3,1.5f, 0,3,2.5f, 0,3,3.5f, 0,3,4.5f, 0,3,5.5f,
  1,0,0, 1,6,6, 2,0,6, 2,6,0, 3,0,0, 3,6,6, 4,0,6, 4,6,0,
  5,0,0, 5,6,6, 6,0,6, 6,6,0, 7,0,0, 7,6,6, 8,0,6, 8,6,0,
  9,0,0, 9,6,6, 10,0,6, 10,6,0, 11,0,0, 11,6,6, 12,0,6, 12,6,0,
  13,0,0, 13,6,6, 14,0,6, 14,6,0, 15,0,0, 15,6,6, 16,0,6, 16,6,0,
  17,0.5f,0.5f, 17,3,0.5f, 17,5.5f,0.5f, 17,0.5f,3, 17,3,3, 17,5.5f,3,
  17,0.5f,5.5f, 17,3,5.5f, 17,5.5f,5.5f
};

struct MKArgs {
  const float *x, *w_in, *b_in, *w_pos, *b_pos, *cls;
  const float *wi, *bi, *wo, *bo, *l1w, *l1b, *f1w, *f1b, *f2w, *f2b, *l2w, *l2b;
  const float *ow, *ob, *m0w, *m0b, *m1w, *m1b, *m2w, *m2b;
  float *h, *o, *out;
  _Float16 *Kp, *Vt, *w1h, *w2h;
};

// ================= shared phase bodies (round-20 math, verbatim) =============

__device__ __forceinline__ void prep_embed_body(const MKArgs& a, int vb, int t) {
  if (vb < 512) {
    int idx = vb * 256 + t;
    a.w1h[idx] = (_Float16)a.f1w[idx];
    int l = idx >> 16, r = idx & 65535, d = r >> 11, ff = r & 2047;
    int dst = ((l * 64 + (ff >> 5)) * 32 + d) * 32 + (ff & 31);
    a.w2h[dst] = (_Float16)a.f2w[idx];
    return;
  }
  int idx = (vb - 512) * 256 + t;
  int r = idx >> 5, d = idx & 31;
  int l = r / NP, n = r - l * NP;
  float v;
  if (n == 0) {
    v = a.cls[d];
  } else {
    int s = n - 1;
    v = a.x[l * NS + s] * a.w_in[d] + a.b_in[d]
      + POSC[s * 3 + 0] * a.w_pos[d * 3 + 0]
      + POSC[s * 3 + 1] * a.w_pos[d * 3 + 1]
      + POSC[s * 3 + 2] * a.w_pos[d * 3 + 2] + a.b_pos[d];
  }
  a.h[idx] = v;
}

__device__ __forceinline__ void kv_body(const MKArgs& a, const float* wi,
                                        const float* bi, int vb, int t, char* arena) {
  float* ws_ = (float*)arena;
  float* bs_ = (float*)(arena + 2048);
  const int nh = vb >> 1;
  const int n = nh >> 2, hh = nh & 3;
  const int l = ((vb & 1) << 8) | t;
  for (int i = t; i < 512; i += 256) {
    int sub = i >> 8, rem = i & 255;
    int jj = rem >> 5, d = rem & 31;
    ws_[i] = wi[((sub + 1) * 32 + hh * 8 + jj) * 32 + d];
  }
  if (t < 16) bs_[t] = bi[((t >> 3) + 1) * 32 + hh * 8 + (t & 7)];
  __syncthreads();
  const float4* hrow = (const float4*)(a.h + (l * NP + n) * 32);
  float4 hv[8];
  #pragma unroll
  for (int i = 0; i < 8; ++i) hv[i] = hrow[i];
  f16x8 kh, kl_, vh;
  #pragma unroll
  for (int jj = 0; jj < 8; ++jj) {
    float k0 = bs_[jj], k1 = 0.f, k2 = 0.f, k3 = 0.f;
    float v0 = bs_[8 + jj], v1 = 0.f, v2 = 0.f, v3 = 0.f;
    #pragma unroll
    for (int d4 = 0; d4 < 8; ++d4) {
      float4 hvv = hv[d4];
      k0 += hvv.x * ws_[jj * 32 + 4 * d4 + 0];
      k1 += hvv.y * ws_[jj * 32 + 4 * d4 + 1];
      k2 += hvv.z * ws_[jj * 32 + 4 * d4 + 2];
      k3 += hvv.w * ws_[jj * 32 + 4 * d4 + 3];
      v0 += hvv.x * ws_[256 + jj * 32 + 4 * d4 + 0];
      v1 += hvv.y * ws_[256 + jj * 32 + 4 * d4 + 1];
      v2 += hvv.z * ws_[256 + jj * 32 + 4 * d4 + 2];
      v3 += hvv.w * ws_[256 + jj * 32 + 4 * d4 + 3];
    }
    float kv = (k0 + k1) + (k2 + k3);
    float vv = (v0 + v1) + (v2 + v3);
    kh[jj] = (_Float16)kv; kl_[jj] = (_Float16)(kv - (float)kh[jj]);
    vh[jj] = (_Float16)vv;
  }
  _Float16* kdst = a.Kp + ((size_t)nh * 512 + l) * 16;
  *(f16x8*)(kdst) = kh;
  *(f16x8*)(kdst + 8) = kl_;
  #pragma unroll
  for (int d = 0; d < 8; ++d) a.Vt[(size_t)nh * 4096 + d * 512 + l] = vh[d];
}

__device__ __forceinline__ void attn_body(const MKArgs& a, const float* wi,
                                          const float* bi, int vb, int t, char* arena) {
  _Float16* khi = (_Float16*)arena;
  _Float16* klo = (_Float16*)(arena + 8192);
  _Float16* vts = (_Float16*)(arena + 16384);
  float* hq_pls = (float*)(arena + 24704);
  _Float16* qf  = (_Float16*)(arena + 43136);
  float* wsq    = (float*)(arena + 47232);
  float* bq     = (float*)(arena + 48256);
  const int nh = vb >> 2, qc = vb & 3;
  const int n = nh >> 2, hh = nh & 3;
  const int lane = t & 63, wv = t >> 6;
  const int c = lane & 15, g = lane >> 4;

  const _Float16* kg = a.Kp + (size_t)nh * 8192;
  for (int r = t; r < 512; r += 256) {
    const uint4* src = (const uint4*)(kg + r * 16);
    uint4 aa = src[0], bb = src[1];
    *(uint4*)(khi + r * 8) = aa;
    *(uint4*)(klo + r * 8) = bb;
  }
  {
    const _Float16* vg = a.Vt + (size_t)nh * 4096;
    for (int i = t; i < 512; i += 256) {
      int d = i >> 6, seg = i & 63;
      *(uint4*)(vts + d * VSTR + seg * 8) = *(const uint4*)(vg + d * 512 + seg * 8);
    }
  }
  wsq[t] = wi[(hh * 8 + (t & 7)) * 32 + (t >> 3)];
  if (t < 8) bq[t] = bi[hh * 8 + t];
  float* hq = hq_pls;

  #pragma unroll
  for (int rp = 0; rp < 2; ++rp) {
    {
      int row = t >> 2, quar = t & 3;
      const float4* src =
          (const float4*)(a.h + (((qc * 128 + rp * 64 + row) * NP) + n) * 32 + quar * 8);
      float4 aa = src[0], bb = src[1];
      __syncthreads();
      *(float4*)(hq + row * 36 + quar * 8) = aa;
      *(float4*)(hq + row * 36 + quar * 8 + 4) = bb;
    }
    __syncthreads();
    {
      int row = t >> 2, pr = t & 3;
      #pragma unroll
      for (int u = 0; u < 2; ++u) {
        int jj = pr * 2 + u;
        float av = bq[jj];
        #pragma unroll
        for (int d = 0; d < 32; ++d) av += hq[row * 36 + d] * wsq[d * 8 + jj];
        _Float16 qh = (_Float16)av;
        _Float16 ql = (_Float16)(av - (float)qh);
        qf[(rp * 64 + row) * 16 + jj] = qh;
        qf[(rp * 64 + row) * 16 + 8 + jj] = ql;
      }
    }
    __syncthreads();
  }

  const f16x8 hz = {(_Float16)0,(_Float16)0,(_Float16)0,(_Float16)0,
                    (_Float16)0,(_Float16)0,(_Float16)0,(_Float16)0};
  const f32x4 zf = {0.f, 0.f, 0.f, 0.f};
  _Float16* pls_ = (_Float16*)hq_pls;
  _Float16* mypA = pls_ + wv * (16 * PSTR);
  _Float16* mypB = pls_ + (4 + wv) * (16 * PSTR);
  const int q0A = qc * 128 + wv * 16;
  const int q0B = q0A + 64;

  f16x8 aqA = hz, aqB = hz;
  if (g < 3) {
    aqA = *(const f16x8*)(qf + (wv * 16 + c) * 16 + (g & 1) * 8);
    aqB = *(const f16x8*)(qf + (64 + wv * 16 + c) * 16 + (g & 1) * 8);
  }
  f32x4 accA = {0.f, 0.f, 0.f, 0.f}, accB = {0.f, 0.f, 0.f, 0.f};
  float lsA[4] = {0.f, 0.f, 0.f, 0.f}, lsB[4] = {0.f, 0.f, 0.f, 0.f};

  for (int ch = 0; ch < 8; ++ch) {
    const int kb = ch * 64;
    #pragma unroll
    for (int kt = 0; kt < 4; ++kt) {
      f16x8 bk = hz;
      if (g < 2)       bk = *(const f16x8*)(khi + (kb + kt * 16 + c) * 8);
      else if (g == 2) bk = *(const f16x8*)(klo + (kb + kt * 16 + c) * 8);
      f32x4 sA = __builtin_amdgcn_mfma_f32_16x16x32_f16(aqA, bk, zf, 0, 0, 0);
      f32x4 sB = __builtin_amdgcn_mfma_f32_16x16x32_f16(aqB, bk, zf, 0, 0, 0);
      #pragma unroll
      for (int r = 0; r < 4; ++r) {
        float pA = __expf(sA[r] * 0.35355339059327373f - 2.0f);
        float pB = __expf(sB[r] * 0.35355339059327373f - 2.0f);
        _Float16 phA = (_Float16)pA;
        _Float16 phB = (_Float16)pB;
        lsA[r] += (float)phA;
        lsB[r] += (float)phB;
        mypA[(g * 4 + r) * PSTR + kt * 16 + c] = phA;
        mypB[(g * 4 + r) * PSTR + kt * 16 + c] = phB;
      }
    }
    #pragma unroll
    for (int half = 0; half < 2; ++half) {
      f16x8 bv = hz;
      if (c < 8) bv = *(const f16x8*)(vts + c * VSTR + kb + half * 32 + g * 8);
      f16x8 apA = *(const f16x8*)(mypA + c * PSTR + half * 32 + g * 8);
      f16x8 apB = *(const f16x8*)(mypB + c * PSTR + half * 32 + g * 8);
      accA = __builtin_amdgcn_mfma_f32_16x16x32_f16(apA, bv, accA, 0, 0, 0);
      accB = __builtin_amdgcn_mfma_f32_16x16x32_f16(apB, bv, accB, 0, 0, 0);
    }
  }
  #pragma unroll
  for (int m = 1; m < 16; m <<= 1) {
    #pragma unroll
    for (int r = 0; r < 4; ++r) {
      lsA[r] += __shfl_xor(lsA[r], m, 64);
      lsB[r] += __shfl_xor(lsB[r], m, 64);
    }
  }
  if (c < 8) {
    #pragma unroll
    for (int r = 0; r < 4; ++r) {
      a.o[((q0A + g * 4 + r) * NP + n) * 32 + hh * 8 + c] = accA[r] / lsA[r];
      a.o[((q0B + g * 4 + r) * NP + n) * 32 + hh * 8 + c] = accB[r] / lsB[r];
    }
  }
}

__device__ __forceinline__ void proj_body(const MKArgs& a, const float* wo,
                                          const float* bo, const float* lw,
                                          const float* lb, int vb, int t, char* arena) {
  float* wos = (float*)arena;
  float* pre = (float*)(arena + 4224);
  for (int i = t; i < 1024; i += 256) wos[(i >> 5) * 33 + (i & 31)] = wo[i];
  __syncthreads();
  const int subr = t >> 2, jq = t & 3;
  const int r = vb * 64 + subr;
  const float4* orow = (const float4*)(a.o + r * 32);
  float4 ov[8];
  #pragma unroll
  for (int i = 0; i < 8; ++i) ov[i] = orow[i];
  const float* hres = a.h + r * 32 + jq * 8;
  #pragma unroll
  for (int jj = 0; jj < 8; ++jj) {
    int j = jq * 8 + jj;
    float a0 = bo[j], a1 = 0.f, a2 = 0.f, a3 = 0.f;
    #pragma unroll
    for (int d4 = 0; d4 < 8; ++d4) {
      float4 vv = ov[d4];
      a0 += vv.x * wos[j * 33 + 4 * d4 + 0];
      a1 += vv.y * wos[j * 33 + 4 * d4 + 1];
      a2 += vv.z * wos[j * 33 + 4 * d4 + 2];
      a3 += vv.w * wos[j * 33 + 4 * d4 + 3];
    }
    pre[subr * 33 + j] = (a0 + a1) + (a2 + a3) + hres[jj];
  }
  __syncthreads();
  if (t < 64) {
    float mu = 0.f;
    #pragma unroll
    for (int d = 0; d < 32; ++d) mu += pre[t * 33 + d];
    mu *= (1.f / 32.f);
    float var = 0.f;
    #pragma unroll
    for (int d = 0; d < 32; ++d) { float dv = pre[t * 33 + d] - mu; var += dv * dv; }
    float rs = rsqrtf(var * (1.f / 32.f) + 1e-5f);
    float* hrow = a.h + (vb * 64 + t) * 32;
    #pragma unroll
    for (int d = 0; d < 32; ++d)
      hrow[d] = (pre[t * 33 + d] - mu) * rs * lw[d] + lb[d];
  }
}

__device__ __forceinline__ void ff_body(const MKArgs& a, const _Float16* w1h,
                                        const float* b1, const _Float16* w2h,
                                        const float* b2, const float* lw,
                                        const float* lb, int do_head, int vb,
                                        int t, char* arena) {
  float* yw    = (float*)arena;
  float* pre_s = (float*)(arena + 25344);
  float* sv1   = (float*)(arena + 31680);
  float* hid   = (float*)(arena + 31872);
  float* red   = (float*)(arena + 32896);
  const int lane = t & 63;
  const int wv = t >> 6;
  const int nl = lane & 15;
  const int g = lane >> 4;
  const int g4 = g * 4;
  const int r0 = vb * FTOK;

  f16x8 hfrag[3];
  #pragma unroll
  for (int tt = 0; tt < 3; ++tt) {
    const float4 h0 = *(const float4*)(a.h + (r0 + tt * 16 + nl) * 32 + g * 8);
    const float4 h1 = *(const float4*)(a.h + (r0 + tt * 16 + nl) * 32 + g * 8 + 4);
    hfrag[tt][0] = (_Float16)h0.x; hfrag[tt][1] = (_Float16)h0.y;
    hfrag[tt][2] = (_Float16)h0.z; hfrag[tt][3] = (_Float16)h0.w;
    hfrag[tt][4] = (_Float16)h1.x; hfrag[tt][5] = (_Float16)h1.y;
    hfrag[tt][6] = (_Float16)h1.z; hfrag[tt][7] = (_Float16)h1.w;
  }

  f32x4 acc0[3], acc1[3];
  #pragma unroll
  for (int tt = 0; tt < 3; ++tt) {
    acc0[tt] = (f32x4){0.f, 0.f, 0.f, 0.f};
    acc1[tt] = (f32x4){0.f, 0.f, 0.f, 0.f};
  }
  const f32x4 zero = {0.f, 0.f, 0.f, 0.f};

  for (int sc = 0; sc < 16; ++sc) {
    const int ffb = wv * 512 + sc * 32;
    f16x8 wf0 = *(const f16x8*)(w1h + (ffb + nl) * 32 + g * 8);
    f16x8 wf1 = *(const f16x8*)(w1h + (ffb + 16 + nl) * 32 + g * 8);
    float4 bv0 = *(const float4*)(b1 + ffb + g4);
    float4 bv1 = *(const float4*)(b1 + ffb + 16 + g4);
    const _Float16* cb = w2h + (ffb >> 5) * 1024;
    f16x4 a0lo = *(const f16x4*)(cb + nl * 32 + g4);
    f16x4 a0hi = *(const f16x4*)(cb + nl * 32 + 16 + g4);
    f16x4 a1lo = *(const f16x4*)(cb + (16 + nl) * 32 + g4);
    f16x4 a1hi = *(const f16x4*)(cb + (16 + nl) * 32 + 16 + g4);
    f16x8 A0, A1;
    #pragma unroll
    for (int j = 0; j < 4; ++j) {
      A0[j] = a0lo[j]; A0[4 + j] = a0hi[j];
      A1[j] = a1lo[j]; A1[4 + j] = a1hi[j];
    }
    #pragma unroll
    for (int tt = 0; tt < 3; ++tt) {
      f32x4 cc0 = __builtin_amdgcn_mfma_f32_16x16x32_f16(wf0, hfrag[tt], zero, 0, 0, 0);
      f32x4 cc1 = __builtin_amdgcn_mfma_f32_16x16x32_f16(wf1, hfrag[tt], zero, 0, 0, 0);
      f16x8 uB;
      uB[0] = (_Float16)fmaxf(cc0[0] + bv0.x, 0.f);
      uB[1] = (_Float16)fmaxf(cc0[1] + bv0.y, 0.f);
      uB[2] = (_Float16)fmaxf(cc0[2] + bv0.z, 0.f);
      uB[3] = (_Float16)fmaxf(cc0[3] + bv0.w, 0.f);
      uB[4] = (_Float16)fmaxf(cc1[0] + bv1.x, 0.f);
      uB[5] = (_Float16)fmaxf(cc1[1] + bv1.y, 0.f);
      uB[6] = (_Float16)fmaxf(cc1[2] + bv1.z, 0.f);
      uB[7] = (_Float16)fmaxf(cc1[3] + bv1.w, 0.f);
      acc0[tt] = __builtin_amdgcn_mfma_f32_16x16x32_f16(A0, uB, acc0[tt], 0, 0, 0);
      acc1[tt] = __builtin_amdgcn_mfma_f32_16x16x32_f16(A1, uB, acc1[tt], 0, 0, 0);
    }
  }
  #pragma unroll
  for (int tt = 0; tt < 3; ++tt) {
    #pragma unroll
    for (int r = 0; r < 4; ++r) {
      yw[wv * (FTOK * 33) + (tt * 16 + nl) * 33 + g4 + r]      = acc0[tt][r];
      yw[wv * (FTOK * 33) + (tt * 16 + nl) * 33 + 16 + g4 + r] = acc1[tt][r];
    }
  }
  __syncthreads();

  {
    int idx = t;
    #pragma unroll
    for (int u = 0; u < 6; ++u, idx += 256) {
      int tok = idx >> 5, d = idx & 31;
      int off = tok * 33 + d;
      float v = yw[off] + yw[FTOK * 33 + off] + yw[2 * FTOK * 33 + off]
              + yw[3 * FTOK * 33 + off] + b2[d] + a.h[(r0 + tok) * 32 + d];
      pre_s[off] = v;
    }
  }
  __syncthreads();

  if (t < FTOK) {
    float mu = 0.f;
    #pragma unroll
    for (int d = 0; d < 32; ++d) mu += pre_s[t * 33 + d];
    mu *= (1.f / 32.f);
    float var = 0.f;
    #pragma unroll
    for (int d = 0; d < 32; ++d) { float dv = pre_s[t * 33 + d] - mu; var += dv * dv; }
    float rs = rsqrtf(var * (1.f / 32.f) + 1e-5f);
    const int rr = r0 + t;
    float* hrow = a.h + (size_t)rr * 32;
    float hn[32];
    #pragma unroll
    for (int d = 0; d < 32; ++d) {
      hn[d] = (pre_s[t * 33 + d] - mu) * rs * lw[d] + lb[d];
      hrow[d] = hn[d];
    }
    if (do_head && t > 0) {
      float av = a.ob[0];
      #pragma unroll
      for (int d = 0; d < 32; ++d) av += hn[d] * a.ow[d];
      sv1[t - 1] = fmaxf(av, 0.f);
    }
  }

  if (do_head) {
    __syncthreads();
    const int l = vb;
    {
      float av = a.m0b[t];
      const float* wr = a.m0w + t * NS;
      #pragma unroll
      for (int s = 0; s < NS; ++s) av += sv1[s] * wr[s];
      hid[t] = fmaxf(av, 0.f);
    }
    __syncthreads();
    {
      float av = a.m1b[t];
      const float4* wr = (const float4*)(a.m1w + t * NHID);
      #pragma unroll 8
      for (int j4 = 0; j4 < 64; ++j4) {
        float4 w = wr[j4];
        av += hid[4 * j4 + 0] * w.x + hid[4 * j4 + 1] * w.y
            + hid[4 * j4 + 2] * w.z + hid[4 * j4 + 3] * w.w;
      }
      float h2 = fmaxf(av, 0.f);
      float part = h2 * a.m2w[t];
      #pragma unroll
      for (int off = 32; off > 0; off >>= 1) part += __shfl_down(part, off, 64);
      if ((t & 63) == 0) red[t >> 6] = part;
    }
    __syncthreads();
    if (t == 0) a.out[l] = fmaxf(red[0] + red[1] + red[2] + red[3] + a.m2b[0], 0.f);
  }
}

// ================= megakernel (cooperative, grid-stride) =====================
__global__ __launch_bounds__(256, 2) void megakernel(MKArgs a) {
  __shared__ alignas(16) char arena[48384];
  cg::grid_group grid = cg::this_grid();
  const int bid = blockIdx.x;
  const int nblk = gridDim.x;
  const int t = threadIdx.x;

  for (int vb = bid; vb < 3584; vb += nblk) prep_embed_body(a, vb, t);
  grid.sync();

  for (int L = 0; L < 2; ++L) {
    const float* wiL = a.wi + L * 3072;
    const float* biL = a.bi + L * 96;
    for (int vb = bid; vb < 384; vb += nblk) {
      kv_body(a, wiL, biL, vb, t, arena);
      __syncthreads();
    }
    grid.sync();
    for (int vb = bid; vb < 768; vb += nblk) {
      attn_body(a, wiL, biL, vb, t, arena);
      __syncthreads();
    }
    grid.sync();
    for (int vb = bid; vb < 384; vb += nblk) {
      proj_body(a, a.wo + L * 1024, a.bo + L * 32,
                a.l1w + L * 32, a.l1b + L * 32, vb, t, arena);
      __syncthreads();
    }
    grid.sync();
    for (int vb = bid; vb < 512; vb += nblk) {
      ff_body(a, a.w1h + L * 65536, a.f1b + L * NFF, a.w2h + L * 65536,
              a.f2b + L * 32, a.l2w + L * 32, a.l2b + L * 32, L, vb, t, arena);
      __syncthreads();
    }
    if (L == 0) grid.sync();
  }
}

// ================= fallback wrappers (round-20 pipeline) =====================
__global__ __launch_bounds__(256) void prep_embed_kernel(MKArgs a) {
  prep_embed_body(a, blockIdx.x, threadIdx.x);
}
__global__ __launch_bounds__(256) void kv_kernel(MKArgs a, int L) {
  __shared__ alignas(16) char arena[2112];
  kv_body(a, a.wi + L * 3072, a.bi + L * 96, blockIdx.x, threadIdx.x, arena);
}
__global__ __launch_bounds__(256, 3) void attn_kernel(MKArgs a, int L) {
  __shared__ alignas(16) char arena[48288];
  attn_body(a, a.wi + L * 3072, a.bi + L * 96, blockIdx.x, threadIdx.x, arena);
}
__global__ __launch_bounds__(256) void proj_kernel(MKArgs a, int L) {
  __shared__ alignas(16) char arena[12672];
  proj_body(a, a.wo + L * 1024, a.bo + L * 32, a.l1w + L * 32, a.l1b + L * 32,
            blockIdx.x, threadIdx.x, arena);
}
__global__ __launch_bounds__(256, 2) void ff_kernel(MKArgs a, int L) {
  __shared__ alignas(16) char arena[32912];
  ff_body(a, a.w1h + L * 65536, a.f1b + L * NFF, a.w2h + L * 65536,
          a.f2b + L * 32, a.l2w + L * 32, a.l2b + L * 32, L,
          blockIdx.x, threadIdx.x, arena);
}

extern "C" void kernel_launch(void* const* d_in, const int* in_sizes, int n_in,
                              void* d_out, int out_size, void* d_ws, size_t ws_size,
                              hipStream_t stream) {
  (void)in_sizes; (void)n_in; (void)out_size; (void)ws_size;
  float* ws = (float*)d_ws;
  MKArgs a;
  a.x     = (const float*)d_in[0];
  a.w_in  = (const float*)d_in[1];
  a.b_in  = (const float*)d_in[2];
  a.w_pos = (const float*)d_in[3];
  a.b_pos = (const float*)d_in[4];
  a.cls   = (const float*)d_in[5];
  a.wi    = (const float*)d_in[6];
  a.bi    = (const float*)d_in[7];
  a.wo    = (const float*)d_in[8];
  a.bo    = (const float*)d_in[9];
  a.l1w   = (const float*)d_in[10];
  a.l1b   = (const float*)d_in[11];
  a.f1w   = (const float*)d_in[12];
  a.f1b   = (const float*)d_in[13];
  a.f2w   = (const float*)d_in[14];
  a.f2b   = (const float*)d_in[15];
  a.l2w   = (const float*)d_in[16];
  a.l2b   = (const float*)d_in[17];
  a.ow    = (const float*)d_in[18];
  a.ob    = (const float*)d_in[19];
  a.m0w   = (const float*)d_in[20];
  a.m0b   = (const float*)d_in[21];
  a.m1w   = (const float*)d_in[22];
  a.m1b   = (const float*)d_in[23];
  a.m2w   = (const float*)d_in[24];
  a.m2b   = (const float*)d_in[25];
  a.out   = (float*)d_out;
  a.h     = ws;
  a.o     = ws + 786432;
  a.Kp    = (_Float16*)(ws + 1572864);
  a.Vt    = (_Float16*)(ws + 1572864 + 786432);
  a.w1h   = (_Float16*)(ws + 2776576);
  a.w2h   = (_Float16*)(ws + 2842112);

  // Try the cooperative megakernel at whatever grid the runtime says fits.
  int occ = 0;
  hipError_t err = hipErrorUnknown;
  hipError_t eo = hipOccupancyMaxActiveBlocksPerMultiprocessor(
      &occ, (const void*)megakernel, 256, 0);
  if (eo == hipSuccess && occ > 0) {
    int nblk = occ * 256;
    if (nblk > 512) nblk = 512;
    void* kp[] = {(void*)&a};
    err = hipLaunchCooperativeKernel((const void*)megakernel, dim3(nblk),
                                     dim3(256), kp, 0, stream);
  }
  if (err != hipSuccess) {
    // Fallback: proven round-20 multi-kernel pipeline (identical math).
    prep_embed_kernel<<<3584, 256, 0, stream>>>(a);
    for (int L = 0; L < 2; ++L) {
      kv_kernel<<<384, 256, 0, stream>>>(a, L);
      attn_kernel<<<768, 256, 0, stream>>>(a, L);
      proj_kernel<<<384, 256, 0, stream>>>(a, L);
      ff_kernel<<<512, 256, 0, stream>>>(a, L);
    }
  }
}

// Round 24
// 150.487 us; speedup vs baseline: 3.1696x; 3.1696x over previous
//
#include <hip/hip_runtime.h>

#define NB 512      // batch = attention sequence length L
#define NS 47
#define NP 48       // positions = attention "batch" N
#define DIM 32
#define NFF 2048
#define NHID 256
#define NROWS (NB * NP)   // 24576
#define FTOK 48     // ff tokens per block = exactly 1 batch element

#define VSTR 520    // V^T LDS row stride (halfs)
#define PSTR 72     // P LDS row stride (halfs)

typedef _Float16 f16x8 __attribute__((ext_vector_type(8)));
typedef _Float16 f16x4 __attribute__((ext_vector_type(4)));
typedef float f32x4 __attribute__((ext_vector_type(4)));

__constant__ float POSC[NS * 3] = {
  0,3,0.5f, 0,3,1.5f, 0,3,2.5f, 0,3,3.5f, 0,3,4.5f, 0,3,5.5f,
  1,0,0, 1,6,6, 2,0,6, 2,6,0, 3,0,0, 3,6,6, 4,0,6, 4,6,0,
  5,0,0, 5,6,6, 6,0,6, 6,6,0, 7,0,0, 7,6,6, 8,0,6, 8,6,0,
  9,0,0, 9,6,6, 10,0,6, 10,6,0, 11,0,0, 11,6,6, 12,0,6, 12,6,0,
  13,0,0, 13,6,6, 14,0,6, 14,6,0, 15,0,0, 15,6,6, 16,0,6, 16,6,0,
  17,0.5f,0.5f, 17,3,0.5f, 17,5.5f,0.5f, 17,0.5f,3, 17,3,3, 17,5.5f,3,
  17,0.5f,5.5f, 17,3,5.5f, 17,5.5f,5.5f
};

// Merged: blocks [0,512) convert f1w (layout kept) and f2w (chunk-tiled) to
// fp16; blocks [512,3584) do embed.
// w2 chunk-tile: w2p[l][chunk=ff>>5][dim][ff&31] -- dense 2 KB per 32-ff chunk.
__global__ __launch_bounds__(256) void prep_embed_kernel(
    const float* __restrict__ w1, const float* __restrict__ w2,
    _Float16* __restrict__ w1h, _Float16* __restrict__ w2h,
    const float* __restrict__ x, const float* __restrict__ w_in,
    const float* __restrict__ b_in, const float* __restrict__ w_pos,
    const float* __restrict__ b_pos, const float* __restrict__ cls,
    float* __restrict__ h) {
  const int bx = blockIdx.x;
  if (bx < 512) {
    int idx = bx * 256 + threadIdx.x;   // exactly 131072
    w1h[idx] = (_Float16)w1[idx];
    int l = idx >> 16, r = idx & 65535, d = r >> 11, ff = r & 2047;
    int dst = ((l * 64 + (ff >> 5)) * 32 + d) * 32 + (ff & 31);
    w2h[dst] = (_Float16)w2[idx];
    return;
  }
  int idx = (bx - 512) * 256 + threadIdx.x;   // exactly 786432
  int r = idx >> 5, d = idx & 31;
  int l = r / NP, n = r - l * NP;
  float v;
  if (n == 0) {
    v = cls[d];
  } else {
    int s = n - 1;
    v = x[l * NS + s] * w_in[d] + b_in[d]
      + POSC[s * 3 + 0] * w_pos[d * 3 + 0]
      + POSC[s * 3 + 1] * w_pos[d * 3 + 1]
      + POSC[s * 3 + 2] * w_pos[d * 3 + 2] + b_pos[d];
  }
  h[idx] = v;
}

// K,V projection. Block = half of one (n,h): 256 rows.
//  Kp[nh][l][16] fp16 (hi 8, lo 8);  Vt[nh][8][512] fp16.
__global__ __launch_bounds__(256) void kv_kernel(
    const float* __restrict__ h, const float* __restrict__ wi, const float* __restrict__ bi,
    _Float16* __restrict__ Kp, _Float16* __restrict__ Vt) {
  __shared__ float ws_[512];
  __shared__ float bs_[16];
  const int t = threadIdx.x;
  const int nh = blockIdx.x >> 1;
  const int n = nh >> 2, hh = nh & 3;
  const int l = ((blockIdx.x & 1) << 8) | t;
  for (int i = t; i < 512; i += 256) {
    int sub = i >> 8, rem = i & 255;
    int jj = rem >> 5, d = rem & 31;
    ws_[i] = wi[((sub + 1) * 32 + hh * 8 + jj) * 32 + d];   // K rows 32..63, V rows 64..95
  }
  if (t < 16) bs_[t] = bi[((t >> 3) + 1) * 32 + hh * 8 + (t & 7)];
  __syncthreads();
  const float4* hrow = (const float4*)(h + (l * NP + n) * 32);
  float4 hv[8];
  #pragma unroll
  for (int i = 0; i < 8; ++i) hv[i] = hrow[i];
  f16x8 kh, kl_, vh;
  #pragma unroll
  for (int jj = 0; jj < 8; ++jj) {
    float k0 = bs_[jj], k1 = 0.f, k2 = 0.f, k3 = 0.f;
    float v0 = bs_[8 + jj], v1 = 0.f, v2 = 0.f, v3 = 0.f;
    #pragma unroll
    for (int d4 = 0; d4 < 8; ++d4) {
      float4 hvv = hv[d4];
      k0 += hvv.x * ws_[jj * 32 + 4 * d4 + 0];
      k1 += hvv.y * ws_[jj * 32 + 4 * d4 + 1];
      k2 += hvv.z * ws_[jj * 32 + 4 * d4 + 2];
      k3 += hvv.w * ws_[jj * 32 + 4 * d4 + 3];
      v0 += hvv.x * ws_[256 + jj * 32 + 4 * d4 + 0];
      v1 += hvv.y * ws_[256 + jj * 32 + 4 * d4 + 1];
      v2 += hvv.z * ws_[256 + jj * 32 + 4 * d4 + 2];
      v3 += hvv.w * ws_[256 + jj * 32 + 4 * d4 + 3];
    }
    float kv = (k0 + k1) + (k2 + k3);
    float vv = (v0 + v1) + (v2 + v3);
    kh[jj] = (_Float16)kv; kl_[jj] = (_Float16)(kv - (float)kh[jj]);
    vh[jj] = (_Float16)vv;
  }
  _Float16* kdst = Kp + ((size_t)nh * 512 + l) * 16;
  *(f16x8*)(kdst) = kh;
  *(f16x8*)(kdst + 8) = kl_;
  #pragma unroll
  for (int d = 0; d < 8; ++d) Vt[(size_t)nh * 4096 + d * 512 + l] = vh[d];
}

// MFMA attention. Block = (n, hh, qc of 128 queries). Phase C: both 64-query
// passes interleaved. LDS 48.3 KB; grid 768 = 3 blocks/CU.
__global__ __launch_bounds__(256, 3) void attn_mfma_kernel(
    const float* __restrict__ h, const float* __restrict__ wi, const float* __restrict__ bi,
    const _Float16* __restrict__ Kp, const _Float16* __restrict__ Vt,
    float* __restrict__ o) {
  __shared__ alignas(16) _Float16 khi[512 * 8];   // 8192 B
  __shared__ alignas(16) _Float16 klo[512 * 8];   // 8192 B
  __shared__ alignas(16) _Float16 vts[8 * VSTR];  // 8320 B
  __shared__ alignas(16) float hq_pls[4608];      // 18432 B
  __shared__ alignas(16) _Float16 qf[128 * 16];   // 4096 B
  __shared__ float wsq[256];
  __shared__ float bq[8];
  const int bx = blockIdx.x;
  const int nh = bx >> 2, qc = bx & 3;
  const int n = nh >> 2, hh = nh & 3;
  const int t = threadIdx.x;
  const int lane = t & 63, wv = t >> 6;
  const int c = lane & 15, g = lane >> 4;

  const _Float16* kg = Kp + (size_t)nh * 8192;
  for (int r = t; r < 512; r += 256) {
    const uint4* src = (const uint4*)(kg + r * 16);
    uint4 a = src[0], b = src[1];
    *(uint4*)(khi + r * 8) = a;
    *(uint4*)(klo + r * 8) = b;
  }
  {
    const _Float16* vg = Vt + (size_t)nh * 4096;
    for (int i = t; i < 512; i += 256) {
      int d = i >> 6, seg = i & 63;
      *(uint4*)(vts + d * VSTR + seg * 8) = *(const uint4*)(vg + d * 512 + seg * 8);
    }
  }
  wsq[t] = wi[(hh * 8 + (t & 7)) * 32 + (t >> 3)];
  if (t < 8) bq[t] = bi[hh * 8 + t];
  float* hq = hq_pls;

  #pragma unroll
  for (int rp = 0; rp < 2; ++rp) {
    {
      int row = t >> 2, quar = t & 3;
      const float4* src =
          (const float4*)(h + (((qc * 128 + rp * 64 + row) * NP) + n) * 32 + quar * 8);
      float4 a = src[0], b = src[1];
      __syncthreads();
      *(float4*)(hq + row * 36 + quar * 8) = a;
      *(float4*)(hq + row * 36 + quar * 8 + 4) = b;
    }
    __syncthreads();
    {
      int row = t >> 2, pr = t & 3;
      #pragma unroll
      for (int u = 0; u < 2; ++u) {
        int jj = pr * 2 + u;
        float a = bq[jj];
        #pragma unroll
        for (int d = 0; d < 32; ++d) a += hq[row * 36 + d] * wsq[d * 8 + jj];
        _Float16 qh = (_Float16)a;
        _Float16 ql = (_Float16)(a - (float)qh);
        qf[(rp * 64 + row) * 16 + jj] = qh;
        qf[(rp * 64 + row) * 16 + 8 + jj] = ql;
      }
    }
    __syncthreads();
  }

  const f16x8 hz = {(_Float16)0,(_Float16)0,(_Float16)0,(_Float16)0,
                    (_Float16)0,(_Float16)0,(_Float16)0,(_Float16)0};
  const f32x4 zf = {0.f, 0.f, 0.f, 0.f};
  _Float16* pls_ = (_Float16*)hq_pls;
  _Float16* mypA = pls_ + wv * (16 * PSTR);
  _Float16* mypB = pls_ + (4 + wv) * (16 * PSTR);
  const int q0A = qc * 128 + wv * 16;
  const int q0B = q0A + 64;

  f16x8 aqA = hz, aqB = hz;
  if (g < 3) {
    aqA = *(const f16x8*)(qf + (wv * 16 + c) * 16 + (g & 1) * 8);
    aqB = *(const f16x8*)(qf + (64 + wv * 16 + c) * 16 + (g & 1) * 8);
  }
  f32x4 accA = {0.f, 0.f, 0.f, 0.f}, accB = {0.f, 0.f, 0.f, 0.f};
  float lsA[4] = {0.f, 0.f, 0.f, 0.f}, lsB[4] = {0.f, 0.f, 0.f, 0.f};

  for (int ch = 0; ch < 8; ++ch) {
    const int kb = ch * 64;
    #pragma unroll
    for (int kt = 0; kt < 4; ++kt) {
      f16x8 bk = hz;
      if (g < 2)       bk = *(const f16x8*)(khi + (kb + kt * 16 + c) * 8);
      else if (g == 2) bk = *(const f16x8*)(klo + (kb + kt * 16 + c) * 8);
      f32x4 sA = __builtin_amdgcn_mfma_f32_16x16x32_f16(aqA, bk, zf, 0, 0, 0);
      f32x4 sB = __builtin_amdgcn_mfma_f32_16x16x32_f16(aqB, bk, zf, 0, 0, 0);
      #pragma unroll
      for (int r = 0; r < 4; ++r) {
        float pA = __expf(sA[r] * 0.35355339059327373f - 2.0f);
        float pB = __expf(sB[r] * 0.35355339059327373f - 2.0f);
        _Float16 phA = (_Float16)pA;
        _Float16 phB = (_Float16)pB;
        lsA[r] += (float)phA;
        lsB[r] += (float)phB;
        mypA[(g * 4 + r) * PSTR + kt * 16 + c] = phA;
        mypB[(g * 4 + r) * PSTR + kt * 16 + c] = phB;
      }
    }
    #pragma unroll
    for (int half = 0; half < 2; ++half) {
      f16x8 bv = hz;
      if (c < 8) bv = *(const f16x8*)(vts + c * VSTR + kb + half * 32 + g * 8);
      f16x8 apA = *(const f16x8*)(mypA + c * PSTR + half * 32 + g * 8);
      f16x8 apB = *(const f16x8*)(mypB + c * PSTR + half * 32 + g * 8);
      accA = __builtin_amdgcn_mfma_f32_16x16x32_f16(apA, bv, accA, 0, 0, 0);
      accB = __builtin_amdgcn_mfma_f32_16x16x32_f16(apB, bv, accB, 0, 0, 0);
    }
  }
  #pragma unroll
  for (int m = 1; m < 16; m <<= 1) {
    #pragma unroll
    for (int r = 0; r < 4; ++r) {
      lsA[r] += __shfl_xor(lsA[r], m, 64);
      lsB[r] += __shfl_xor(lsB[r], m, 64);
    }
  }
  if (c < 8) {
    #pragma unroll
    for (int r = 0; r < 4; ++r) {
      o[((q0A + g * 4 + r) * NP + n) * 32 + hh * 8 + c] = accA[r] / lsA[r];
      o[((q0B + g * 4 + r) * NP + n) * 32 + hh * 8 + c] = accB[r] / lsB[r];
    }
  }
}

// out-proj + residual + LN1, in-place on h. Block = 64 rows.
__global__ __launch_bounds__(256) void proj_ln1_kernel(
    const float* __restrict__ o, const float* __restrict__ wo, const float* __restrict__ bo,
    const float* __restrict__ lw, const float* __restrict__ lb, float* __restrict__ h) {
  __shared__ float wos[32 * 33];
  __shared__ float pre[64 * 33];
  const int g = blockIdx.x, t = threadIdx.x;
  for (int i = t; i < 1024; i += 256) wos[(i >> 5) * 33 + (i & 31)] = wo[i];
  __syncthreads();
  const int subr = t >> 2, jq = t & 3;
  const int r = g * 64 + subr;
  const float4* orow = (const float4*)(o + r * 32);
  float4 ov[8];
  #pragma unroll
  for (int i = 0; i < 8; ++i) ov[i] = orow[i];
  const float* hres = h + r * 32 + jq * 8;
  #pragma unroll
  for (int jj = 0; jj < 8; ++jj) {
    int j = jq * 8 + jj;
    float a0 = bo[j], a1 = 0.f, a2 = 0.f, a3 = 0.f;
    #pragma unroll
    for (int d4 = 0; d4 < 8; ++d4) {
      float4 vv = ov[d4];
      a0 += vv.x * wos[j * 33 + 4 * d4 + 0];
      a1 += vv.y * wos[j * 33 + 4 * d4 + 1];
      a2 += vv.z * wos[j * 33 + 4 * d4 + 2];
      a3 += vv.w * wos[j * 33 + 4 * d4 + 3];
    }
    pre[subr * 33 + j] = (a0 + a1) + (a2 + a3) + hres[jj];
  }
  __syncthreads();
  if (t < 64) {
    float mu = 0.f;
    #pragma unroll
    for (int d = 0; d < 32; ++d) mu += pre[t * 33 + d];
    mu *= (1.f / 32.f);
    float var = 0.f;
    #pragma unroll
    for (int d = 0; d < 32; ++d) { float dv = pre[t * 33 + d] - mu; var += dv * dv; }
    float rs = rsqrtf(var * (1.f / 32.f) + 1e-5f);
    float* hrow = h + (g * 64 + t) * 32;
    #pragma unroll
    for (int d = 0; d < 32; ++d)
      hrow[d] = (pre[t * 33 + d] - mu) * rs * lw[d] + lb[d];
  }
}

// Fused FF + bias + residual + LN2 (+head on last layer). Round-24 = round-20
// with ONE change: the sc chunk loop is STAGGERED per block (sc = (i + bid)
// & 15), so the 512 concurrent blocks touch 16 different weight regions
// instead of hammering the same L2 lines in lockstep (the last untested
// invariant of the schedule-independent ~40us ff wall: L2 serves each CU's
// request for the same line separately -> hot-line serialization).
__global__ __launch_bounds__(256, 2) void ff_fused_kernel(
    const float* __restrict__ h, const _Float16* __restrict__ w1h,
    const float* __restrict__ b1, const _Float16* __restrict__ w2h,
    const float* __restrict__ b2, const float* __restrict__ lw,
    const float* __restrict__ lb, const float* __restrict__ ow,
    const float* __restrict__ ob,
    const float* __restrict__ m0w, const float* __restrict__ m0b,
    const float* __restrict__ m1w, const float* __restrict__ m1b,
    const float* __restrict__ m2w, const float* __restrict__ m2b,
    float* __restrict__ out, int do_head) {
  __shared__ alignas(16) float yw[4][FTOK * 33];   // 25344 B
  __shared__ alignas(16) float pre_s[FTOK * 33];   // 6336 B
  __shared__ float sv1[48];
  __shared__ float hid[NHID];
  __shared__ float red[4];
  const int t = threadIdx.x;
  const int lane = t & 63;
  const int wv = t >> 6;
  const int nl = lane & 15;
  const int g = lane >> 4;
  const int g4 = g * 4;
  const int r0 = blockIdx.x * FTOK;
  const int scoff = blockIdx.x & 15;   // per-block chunk-order stagger

  f16x8 hfrag[3];
  #pragma unroll
  for (int tt = 0; tt < 3; ++tt) {
    const float4 h0 = *(const float4*)(h + (r0 + tt * 16 + nl) * 32 + g * 8);
    const float4 h1 = *(const float4*)(h + (r0 + tt * 16 + nl) * 32 + g * 8 + 4);
    hfrag[tt][0] = (_Float16)h0.x; hfrag[tt][1] = (_Float16)h0.y;
    hfrag[tt][2] = (_Float16)h0.z; hfrag[tt][3] = (_Float16)h0.w;
    hfrag[tt][4] = (_Float16)h1.x; hfrag[tt][5] = (_Float16)h1.y;
    hfrag[tt][6] = (_Float16)h1.z; hfrag[tt][7] = (_Float16)h1.w;
  }

  f32x4 acc0[3], acc1[3];
  #pragma unroll
  for (int tt = 0; tt < 3; ++tt) {
    acc0[tt] = (f32x4){0.f, 0.f, 0.f, 0.f};
    acc1[tt] = (f32x4){0.f, 0.f, 0.f, 0.f};
  }
  const f32x4 zero = {0.f, 0.f, 0.f, 0.f};

  for (int si = 0; si < 16; ++si) {
    const int sc = (si + scoff) & 15;   // staggered chunk order
    const int ffb = wv * 512 + sc * 32;
    // GEMM1 A-frags (w1 rows = ff)
    f16x8 wf0 = *(const f16x8*)(w1h + (ffb + nl) * 32 + g * 8);
    f16x8 wf1 = *(const f16x8*)(w1h + (ffb + 16 + nl) * 32 + g * 8);
    // biases for pack slots
    float4 bv0 = *(const float4*)(b1 + ffb + g4);
    float4 bv1 = *(const float4*)(b1 + ffb + 16 + g4);
    // GEMM2 A-frags: w2[dim][ff] with the SAME per-lane ff permutation as B
    const _Float16* cb = w2h + (ffb >> 5) * 1024;   // chunk-tiled [dim][ff&31]
    f16x4 a0lo = *(const f16x4*)(cb + nl * 32 + g4);
    f16x4 a0hi = *(const f16x4*)(cb + nl * 32 + 16 + g4);
    f16x4 a1lo = *(const f16x4*)(cb + (16 + nl) * 32 + g4);
    f16x4 a1hi = *(const f16x4*)(cb + (16 + nl) * 32 + 16 + g4);
    f16x8 A0, A1;
    #pragma unroll
    for (int j = 0; j < 4; ++j) {
      A0[j] = a0lo[j]; A0[4 + j] = a0hi[j];
      A1[j] = a1lo[j]; A1[4 + j] = a1hi[j];
    }
    #pragma unroll
    for (int tt = 0; tt < 3; ++tt) {
      f32x4 cc0 = __builtin_amdgcn_mfma_f32_16x16x32_f16(wf0, hfrag[tt], zero, 0, 0, 0);
      f32x4 cc1 = __builtin_amdgcn_mfma_f32_16x16x32_f16(wf1, hfrag[tt], zero, 0, 0, 0);
      f16x8 uB;
      uB[0] = (_Float16)fmaxf(cc0[0] + bv0.x, 0.f);
      uB[1] = (_Float16)fmaxf(cc0[1] + bv0.y, 0.f);
      uB[2] = (_Float16)fmaxf(cc0[2] + bv0.z, 0.f);
      uB[3] = (_Float16)fmaxf(cc0[3] + bv0.w, 0.f);
      uB[4] = (_Float16)fmaxf(cc1[0] + bv1.x, 0.f);
      uB[5] = (_Float16)fmaxf(cc1[1] + bv1.y, 0.f);
      uB[6] = (_Float16)fmaxf(cc1[2] + bv1.z, 0.f);
      uB[7] = (_Float16)fmaxf(cc1[3] + bv1.w, 0.f);
      acc0[tt] = __builtin_amdgcn_mfma_f32_16x16x32_f16(A0, uB, acc0[tt], 0, 0, 0);
      acc1[tt] = __builtin_amdgcn_mfma_f32_16x16x32_f16(A1, uB, acc1[tt], 0, 0, 0);
    }
  }
  // per-wave partials -> LDS. C layout: acc0[tt][r] = y[tok=nl][dim=g4+r],
  // acc1[tt][r] = y[tok=nl][dim=16+g4+r].
  #pragma unroll
  for (int tt = 0; tt < 3; ++tt) {
    #pragma unroll
    for (int r = 0; r < 4; ++r) {
      yw[wv][(tt * 16 + nl) * 33 + g4 + r]      = acc0[tt][r];
      yw[wv][(tt * 16 + nl) * 33 + 16 + g4 + r] = acc1[tt][r];
    }
  }
  __syncthreads();

  // reduce 4 wave partials + b2 + residual -> pre_s
  {
    int idx = t;               // 1536 outputs, 6 per thread
    #pragma unroll
    for (int u = 0; u < 6; ++u, idx += 256) {
      int tok = idx >> 5, d = idx & 31;
      int off = tok * 33 + d;
      float v = yw[0][off] + yw[1][off] + yw[2][off] + yw[3][off]
              + b2[d] + h[(r0 + tok) * 32 + d];
      pre_s[off] = v;
    }
  }
  __syncthreads();

  if (t < FTOK) {
    float mu = 0.f;
    #pragma unroll
    for (int d = 0; d < 32; ++d) mu += pre_s[t * 33 + d];
    mu *= (1.f / 32.f);
    float var = 0.f;
    #pragma unroll
    for (int d = 0; d < 32; ++d) { float dv = pre_s[t * 33 + d] - mu; var += dv * dv; }
    float rs = rsqrtf(var * (1.f / 32.f) + 1e-5f);
    const int rr = r0 + t;
    float* hrow = (float*)h + (size_t)rr * 32;
    float hn[32];
    #pragma unroll
    for (int d = 0; d < 32; ++d) {
      hn[d] = (pre_s[t * 33 + d] - mu) * rs * lw[d] + lb[d];
      hrow[d] = hn[d];
    }
    if (do_head && t > 0) {   // block rows = batch element blockIdx.x; n = t
      float a = ob[0];
      #pragma unroll
      for (int d = 0; d < 32; ++d) a += hn[d] * ow[d];
      sv1[t - 1] = fmaxf(a, 0.f);
    }
  }

  // ---- fused head MLP for the block's batch element (L=1 only) ----
  if (do_head) {
    __syncthreads();   // sv1 complete
    const int l = blockIdx.x;
    {
      float a = m0b[t];
      const float* wr = m0w + t * NS;
      #pragma unroll
      for (int s = 0; s < NS; ++s) a += sv1[s] * wr[s];
      hid[t] = fmaxf(a, 0.f);
    }
    __syncthreads();
    {
      float a = m1b[t];
      const float4* wr = (const float4*)(m1w + t * NHID);
      #pragma unroll 8
      for (int j4 = 0; j4 < 64; ++j4) {
        float4 w = wr[j4];
        a += hid[4 * j4 + 0] * w.x + hid[4 * j4 + 1] * w.y
           + hid[4 * j4 + 2] * w.z + hid[4 * j4 + 3] * w.w;
      }
      float h2 = fmaxf(a, 0.f);
      float part = h2 * m2w[t];
      #pragma unroll
      for (int off = 32; off > 0; off >>= 1) part += __shfl_down(part, off, 64);
      if ((t & 63) == 0) red[t >> 6] = part;
    }
    __syncthreads();
    if (t == 0) out[l] = fmaxf(red[0] + red[1] + red[2] + red[3] + m2b[0], 0.f);
  }
}

extern "C" void kernel_launch(void* const* d_in, const int* in_sizes, int n_in,
                              void* d_out, int out_size, void* d_ws, size_t ws_size,
                              hipStream_t stream) {
  (void)in_sizes; (void)n_in; (void)out_size; (void)ws_size;
  const float* x     = (const float*)d_in[0];
  const float* w_in  = (const float*)d_in[1];
  const float* b_in  = (const float*)d_in[2];
  const float* w_pos = (const float*)d_in[3];
  const float* b_pos = (const float*)d_in[4];
  const float* cls   = (const float*)d_in[5];
  const float* wi    = (const float*)d_in[6];
  const float* bi    = (const float*)d_in[7];
  const float* wo    = (const float*)d_in[8];
  const float* bo    = (const float*)d_in[9];
  const float* l1w   = (const float*)d_in[10];
  const float* l1b   = (const float*)d_in[11];
  const float* f1w   = (const float*)d_in[12];
  const float* f1b   = (const float*)d_in[13];
  const float* f2w   = (const float*)d_in[14];
  const float* f2b   = (const float*)d_in[15];
  const float* l2w   = (const float*)d_in[16];
  const float* l2b   = (const float*)d_in[17];
  const float* ow    = (const float*)d_in[18];
  const float* ob    = (const float*)d_in[19];
  const float* m0w   = (const float*)d_in[20];
  const float* m0b   = (const float*)d_in[21];
  const float* m1w   = (const float*)d_in[22];
  const float* m1b   = (const float*)d_in[23];
  const float* m2w   = (const float*)d_in[24];
  const float* m2b   = (const float*)d_in[25];
  float* out = (float*)d_out;

  float* ws   = (float*)d_ws;
  float* h    = ws;                           // [0, 786432)
  float* o    = ws + 786432;                  // [786432, 1572864)
  float* R2   = ws + 1572864;                 // [1572864, 2752512)
  _Float16* Kp = (_Float16*)R2;
  _Float16* Vt = (_Float16*)(R2 + 786432);
  _Float16* w1h = (_Float16*)(ws + 2776576);  // 65536 f32 slots
  _Float16* w2h = (_Float16*)(ws + 2842112);  // 65536 f32 slots -> end 2907648

  prep_embed_kernel<<<3584, 256, 0, stream>>>(f1w, f2w, w1h, w2h,
                                              x, w_in, b_in, w_pos, b_pos, cls, h);
  for (int L = 0; L < 2; ++L) {
    kv_kernel<<<384, 256, 0, stream>>>(h, wi + L * 3072, bi + L * 96, Kp, Vt);
    attn_mfma_kernel<<<768, 256, 0, stream>>>(h, wi + L * 3072, bi + L * 96, Kp, Vt, o);
    proj_ln1_kernel<<<384, 256, 0, stream>>>(o, wo + L * 1024, bo + L * 32,
                                             l1w + L * 32, l1b + L * 32, h);
    ff_fused_kernel<<<512, 256, 0, stream>>>(h, w1h + L * 65536, f1b + L * NFF,
                                             w2h + L * 65536, f2b + L * 32,
                                             l2w + L * 32, l2b + L * 32,
                                             ow, ob, m0w, m0b, m1w, m1b, m2w, m2b,
                                             out, L);
  }
}

// Round 25
// 144.141 us; speedup vs baseline: 3.3092x; 1.0440x over previous
//
#include <hip/hip_runtime.h>

#define NB 512      // batch = attention sequence length L
#define NS 47
#define NP 48       // positions = attention "batch" N
#define DIM 32
#define NFF 2048
#define NHID 256
#define NROWS (NB * NP)   // 24576
#define FTOK 48     // ff tokens per block = exactly 1 batch element

#define VSTR 520    // V^T LDS row stride (halfs)
#define PSTR 72     // P LDS row stride (halfs)

typedef _Float16 f16x8 __attribute__((ext_vector_type(8)));
typedef _Float16 f16x4 __attribute__((ext_vector_type(4)));
typedef float f32x4 __attribute__((ext_vector_type(4)));

__constant__ float POSC[NS * 3] = {
  0,3,0.5f, 0,3,1.5f, 0,3,2.5f, 0,3,3.5f, 0,3,4.5f, 0,3,5.5f,
  1,0,0, 1,6,6, 2,0,6, 2,6,0, 3,0,0, 3,6,6, 4,0,6, 4,6,0,
  5,0,0, 5,6,6, 6,0,6, 6,6,0, 7,0,0, 7,6,6, 8,0,6, 8,6,0,
  9,0,0, 9,6,6, 10,0,6, 10,6,0, 11,0,0, 11,6,6, 12,0,6, 12,6,0,
  13,0,0, 13,6,6, 14,0,6, 14,6,0, 15,0,0, 15,6,6, 16,0,6, 16,6,0,
  17,0.5f,0.5f, 17,3,0.5f, 17,5.5f,0.5f, 17,0.5f,3, 17,3,3, 17,5.5f,3,
  17,0.5f,5.5f, 17,3,5.5f, 17,5.5f,5.5f
};

// Merged: blocks [0,512) convert f1w (layout kept) and f2w (chunk-tiled) to
// fp16; blocks [512,3584) do embed.
__global__ __launch_bounds__(256) void prep_embed_kernel(
    const float* __restrict__ w1, const float* __restrict__ w2,
    _Float16* __restrict__ w1h, _Float16* __restrict__ w2h,
    const float* __restrict__ x, const float* __restrict__ w_in,
    const float* __restrict__ b_in, const float* __restrict__ w_pos,
    const float* __restrict__ b_pos, const float* __restrict__ cls,
    float* __restrict__ h) {
  const int bx = blockIdx.x;
  if (bx < 512) {
    int idx = bx * 256 + threadIdx.x;   // exactly 131072
    w1h[idx] = (_Float16)w1[idx];
    int l = idx >> 16, r = idx & 65535, d = r >> 11, ff = r & 2047;
    int dst = ((l * 64 + (ff >> 5)) * 32 + d) * 32 + (ff & 31);
    w2h[dst] = (_Float16)w2[idx];
    return;
  }
  int idx = (bx - 512) * 256 + threadIdx.x;   // exactly 786432
  int r = idx >> 5, d = idx & 31;
  int l = r / NP, n = r - l * NP;
  float v;
  if (n == 0) {
    v = cls[d];
  } else {
    int s = n - 1;
    v = x[l * NS + s] * w_in[d] + b_in[d]
      + POSC[s * 3 + 0] * w_pos[d * 3 + 0]
      + POSC[s * 3 + 1] * w_pos[d * 3 + 1]
      + POSC[s * 3 + 2] * w_pos[d * 3 + 2] + b_pos[d];
  }
  h[idx] = v;
}

// K,V projection. Block = half of one (n,h): 256 rows.
//  Kp[nh][l][16] fp16 (hi 8, lo 8);  Vt[nh][8][512] fp16.
__global__ __launch_bounds__(256) void kv_kernel(
    const float* __restrict__ h, const float* __restrict__ wi, const float* __restrict__ bi,
    _Float16* __restrict__ Kp, _Float16* __restrict__ Vt) {
  __shared__ float ws_[512];
  __shared__ float bs_[16];
  const int t = threadIdx.x;
  const int nh = blockIdx.x >> 1;
  const int n = nh >> 2, hh = nh & 3;
  const int l = ((blockIdx.x & 1) << 8) | t;
  for (int i = t; i < 512; i += 256) {
    int sub = i >> 8, rem = i & 255;
    int jj = rem >> 5, d = rem & 31;
    ws_[i] = wi[((sub + 1) * 32 + hh * 8 + jj) * 32 + d];   // K rows 32..63, V rows 64..95
  }
  if (t < 16) bs_[t] = bi[((t >> 3) + 1) * 32 + hh * 8 + (t & 7)];
  __syncthreads();
  const float4* hrow = (const float4*)(h + (l * NP + n) * 32);
  float4 hv[8];
  #pragma unroll
  for (int i = 0; i < 8; ++i) hv[i] = hrow[i];
  f16x8 kh, kl_, vh;
  #pragma unroll
  for (int jj = 0; jj < 8; ++jj) {
    float k0 = bs_[jj], k1 = 0.f, k2 = 0.f, k3 = 0.f;
    float v0 = bs_[8 + jj], v1 = 0.f, v2 = 0.f, v3 = 0.f;
    #pragma unroll
    for (int d4 = 0; d4 < 8; ++d4) {
      float4 hvv = hv[d4];
      k0 += hvv.x * ws_[jj * 32 + 4 * d4 + 0];
      k1 += hvv.y * ws_[jj * 32 + 4 * d4 + 1];
      k2 += hvv.z * ws_[jj * 32 + 4 * d4 + 2];
      k3 += hvv.w * ws_[jj * 32 + 4 * d4 + 3];
      v0 += hvv.x * ws_[256 + jj * 32 + 4 * d4 + 0];
      v1 += hvv.y * ws_[256 + jj * 32 + 4 * d4 + 1];
      v2 += hvv.z * ws_[256 + jj * 32 + 4 * d4 + 2];
      v3 += hvv.w * ws_[256 + jj * 32 + 4 * d4 + 3];
    }
    float kv = (k0 + k1) + (k2 + k3);
    float vv = (v0 + v1) + (v2 + v3);
    kh[jj] = (_Float16)kv; kl_[jj] = (_Float16)(kv - (float)kh[jj]);
    vh[jj] = (_Float16)vv;
  }
  _Float16* kdst = Kp + ((size_t)nh * 512 + l) * 16;
  *(f16x8*)(kdst) = kh;
  *(f16x8*)(kdst + 8) = kl_;
  #pragma unroll
  for (int d = 0; d < 8; ++d) Vt[(size_t)nh * 4096 + d * 512 + l] = vh[d];
}

// MFMA attention. Block = (n, hh, qc of 128 queries). Phase C: both 64-query
// passes interleaved. LDS 48.3 KB; grid 768 = 3 blocks/CU.
__global__ __launch_bounds__(256, 3) void attn_mfma_kernel(
    const float* __restrict__ h, const float* __restrict__ wi, const float* __restrict__ bi,
    const _Float16* __restrict__ Kp, const _Float16* __restrict__ Vt,
    float* __restrict__ o) {
  __shared__ alignas(16) _Float16 khi[512 * 8];   // 8192 B
  __shared__ alignas(16) _Float16 klo[512 * 8];   // 8192 B
  __shared__ alignas(16) _Float16 vts[8 * VSTR];  // 8320 B
  __shared__ alignas(16) float hq_pls[4608];      // 18432 B
  __shared__ alignas(16) _Float16 qf[128 * 16];   // 4096 B
  __shared__ float wsq[256];
  __shared__ float bq[8];
  const int bx = blockIdx.x;
  const int nh = bx >> 2, qc = bx & 3;
  const int n = nh >> 2, hh = nh & 3;
  const int t = threadIdx.x;
  const int lane = t & 63, wv = t >> 6;
  const int c = lane & 15, g = lane >> 4;

  const _Float16* kg = Kp + (size_t)nh * 8192;
  for (int r = t; r < 512; r += 256) {
    const uint4* src = (const uint4*)(kg + r * 16);
    uint4 a = src[0], b = src[1];
    *(uint4*)(khi + r * 8) = a;
    *(uint4*)(klo + r * 8) = b;
  }
  {
    const _Float16* vg = Vt + (size_t)nh * 4096;
    for (int i = t; i < 512; i += 256) {
      int d = i >> 6, seg = i & 63;
      *(uint4*)(vts + d * VSTR + seg * 8) = *(const uint4*)(vg + d * 512 + seg * 8);
    }
  }
  wsq[t] = wi[(hh * 8 + (t & 7)) * 32 + (t >> 3)];
  if (t < 8) bq[t] = bi[hh * 8 + t];
  float* hq = hq_pls;

  #pragma unroll
  for (int rp = 0; rp < 2; ++rp) {
    {
      int row = t >> 2, quar = t & 3;
      const float4* src =
          (const float4*)(h + (((qc * 128 + rp * 64 + row) * NP) + n) * 32 + quar * 8);
      float4 a = src[0], b = src[1];
      __syncthreads();
      *(float4*)(hq + row * 36 + quar * 8) = a;
      *(float4*)(hq + row * 36 + quar * 8 + 4) = b;
    }
    __syncthreads();
    {
      int row = t >> 2, pr = t & 3;
      #pragma unroll
      for (int u = 0; u < 2; ++u) {
        int jj = pr * 2 + u;
        float a = bq[jj];
        #pragma unroll
        for (int d = 0; d < 32; ++d) a += hq[row * 36 + d] * wsq[d * 8 + jj];
        _Float16 qh = (_Float16)a;
        _Float16 ql = (_Float16)(a - (float)qh);
        qf[(rp * 64 + row) * 16 + jj] = qh;
        qf[(rp * 64 + row) * 16 + 8 + jj] = ql;
      }
    }
    __syncthreads();
  }

  const f16x8 hz = {(_Float16)0,(_Float16)0,(_Float16)0,(_Float16)0,
                    (_Float16)0,(_Float16)0,(_Float16)0,(_Float16)0};
  const f32x4 zf = {0.f, 0.f, 0.f, 0.f};
  _Float16* pls_ = (_Float16*)hq_pls;
  _Float16* mypA = pls_ + wv * (16 * PSTR);
  _Float16* mypB = pls_ + (4 + wv) * (16 * PSTR);
  const int q0A = qc * 128 + wv * 16;
  const int q0B = q0A + 64;

  f16x8 aqA = hz, aqB = hz;
  if (g < 3) {
    aqA = *(const f16x8*)(qf + (wv * 16 + c) * 16 + (g & 1) * 8);
    aqB = *(const f16x8*)(qf + (64 + wv * 16 + c) * 16 + (g & 1) * 8);
  }
  f32x4 accA = {0.f, 0.f, 0.f, 0.f}, accB = {0.f, 0.f, 0.f, 0.f};
  float lsA[4] = {0.f, 0.f, 0.f, 0.f}, lsB[4] = {0.f, 0.f, 0.f, 0.f};

  for (int ch = 0; ch < 8; ++ch) {
    const int kb = ch * 64;
    #pragma unroll
    for (int kt = 0; kt < 4; ++kt) {
      f16x8 bk = hz;
      if (g < 2)       bk = *(const f16x8*)(khi + (kb + kt * 16 + c) * 8);
      else if (g == 2) bk = *(const f16x8*)(klo + (kb + kt * 16 + c) * 8);
      f32x4 sA = __builtin_amdgcn_mfma_f32_16x16x32_f16(aqA, bk, zf, 0, 0, 0);
      f32x4 sB = __builtin_amdgcn_mfma_f32_16x16x32_f16(aqB, bk, zf, 0, 0, 0);
      #pragma unroll
      for (int r = 0; r < 4; ++r) {
        float pA = __expf(sA[r] * 0.35355339059327373f - 2.0f);
        float pB = __expf(sB[r] * 0.35355339059327373f - 2.0f);
        _Float16 phA = (_Float16)pA;
        _Float16 phB = (_Float16)pB;
        lsA[r] += (float)phA;
        lsB[r] += (float)phB;
        mypA[(g * 4 + r) * PSTR + kt * 16 + c] = phA;
        mypB[(g * 4 + r) * PSTR + kt * 16 + c] = phB;
      }
    }
    #pragma unroll
    for (int half = 0; half < 2; ++half) {
      f16x8 bv = hz;
      if (c < 8) bv = *(const f16x8*)(vts + c * VSTR + kb + half * 32 + g * 8);
      f16x8 apA = *(const f16x8*)(mypA + c * PSTR + half * 32 + g * 8);
      f16x8 apB = *(const f16x8*)(mypB + c * PSTR + half * 32 + g * 8);
      accA = __builtin_amdgcn_mfma_f32_16x16x32_f16(apA, bv, accA, 0, 0, 0);
      accB = __builtin_amdgcn_mfma_f32_16x16x32_f16(apB, bv, accB, 0, 0, 0);
    }
  }
  #pragma unroll
  for (int m = 1; m < 16; m <<= 1) {
    #pragma unroll
    for (int r = 0; r < 4; ++r) {
      lsA[r] += __shfl_xor(lsA[r], m, 64);
      lsB[r] += __shfl_xor(lsB[r], m, 64);
    }
  }
  if (c < 8) {
    #pragma unroll
    for (int r = 0; r < 4; ++r) {
      o[((q0A + g * 4 + r) * NP + n) * 32 + hh * 8 + c] = accA[r] / lsA[r];
      o[((q0B + g * 4 + r) * NP + n) * 32 + hh * 8 + c] = accB[r] / lsB[r];
    }
  }
}

// Fused [out-proj + residual + LN1] + FF + bias + residual + LN2 (+head on
// last layer). Round-25: proj_ln1 folded into ff's prologue (row-local work,
// same 48 rows); the LN1 result lives ONLY in LDS (h1) -- global h keeps
// pre-LN1 values until the final LN2 write. Removes 2 dispatches + the h
// round-trip. All math copied verbatim from the proven round-24 kernels ->
// bitwise-identical output.
__global__ __launch_bounds__(256, 2) void ff_fused_kernel(
    const float* __restrict__ h, const float* __restrict__ o,
    const float* __restrict__ wo, const float* __restrict__ bo,
    const float* __restrict__ l1w, const float* __restrict__ l1b,
    const _Float16* __restrict__ w1h, const float* __restrict__ b1,
    const _Float16* __restrict__ w2h, const float* __restrict__ b2,
    const float* __restrict__ lw, const float* __restrict__ lb,
    const float* __restrict__ ow, const float* __restrict__ ob,
    const float* __restrict__ m0w, const float* __restrict__ m0b,
    const float* __restrict__ m1w, const float* __restrict__ m1b,
    const float* __restrict__ m2w, const float* __restrict__ m2b,
    float* __restrict__ out, int do_head) {
  __shared__ alignas(16) float wos[32 * 33];       // 4224 B (prologue)
  __shared__ alignas(16) float h1[FTOK * 33];      // 6336 B (LN1 rows, LDS-only)
  __shared__ alignas(16) float yw[4][FTOK * 33];   // 25344 B
  __shared__ alignas(16) float pre_s[FTOK * 33];   // 6336 B (also prologue pre)
  __shared__ float sv1[48];
  __shared__ float hid[NHID];
  __shared__ float red[4];
  const int t = threadIdx.x;
  const int lane = t & 63;
  const int wv = t >> 6;
  const int nl = lane & 15;
  const int g = lane >> 4;
  const int g4 = g * 4;
  const int r0 = blockIdx.x * FTOK;
  const int scoff = blockIdx.x & 15;

  // ---- prologue: out-proj + residual -> pre_s; LN1 -> h1 (proj math verbatim)
  for (int i = t; i < 1024; i += 256) wos[(i >> 5) * 33 + (i & 31)] = wo[i];
  __syncthreads();
  {
    const int subr = t >> 2, jq = t & 3;
    if (subr < FTOK) {
      const int r = r0 + subr;
      const float4* orow = (const float4*)(o + r * 32);
      float4 ov[8];
      #pragma unroll
      for (int i = 0; i < 8; ++i) ov[i] = orow[i];
      const float* hres = h + r * 32 + jq * 8;
      #pragma unroll
      for (int jj = 0; jj < 8; ++jj) {
        int j = jq * 8 + jj;
        float a0 = bo[j], a1 = 0.f, a2 = 0.f, a3 = 0.f;
        #pragma unroll
        for (int d4 = 0; d4 < 8; ++d4) {
          float4 vv = ov[d4];
          a0 += vv.x * wos[j * 33 + 4 * d4 + 0];
          a1 += vv.y * wos[j * 33 + 4 * d4 + 1];
          a2 += vv.z * wos[j * 33 + 4 * d4 + 2];
          a3 += vv.w * wos[j * 33 + 4 * d4 + 3];
        }
        pre_s[subr * 33 + j] = (a0 + a1) + (a2 + a3) + hres[jj];
      }
    }
  }
  __syncthreads();
  if (t < FTOK) {
    float mu = 0.f;
    #pragma unroll
    for (int d = 0; d < 32; ++d) mu += pre_s[t * 33 + d];
    mu *= (1.f / 32.f);
    float var = 0.f;
    #pragma unroll
    for (int d = 0; d < 32; ++d) { float dv = pre_s[t * 33 + d] - mu; var += dv * dv; }
    float rs = rsqrtf(var * (1.f / 32.f) + 1e-5f);
    #pragma unroll
    for (int d = 0; d < 32; ++d)
      h1[t * 33 + d] = (pre_s[t * 33 + d] - mu) * rs * l1w[d] + l1b[d];
  }
  __syncthreads();

  // ---- FF main loop (round-24 verbatim; h-row reads -> h1 in LDS) ----
  f16x8 hfrag[3];
  #pragma unroll
  for (int tt = 0; tt < 3; ++tt) {
    #pragma unroll
    for (int e = 0; e < 8; ++e)
      hfrag[tt][e] = (_Float16)h1[(tt * 16 + nl) * 33 + g * 8 + e];
  }

  f32x4 acc0[3], acc1[3];
  #pragma unroll
  for (int tt = 0; tt < 3; ++tt) {
    acc0[tt] = (f32x4){0.f, 0.f, 0.f, 0.f};
    acc1[tt] = (f32x4){0.f, 0.f, 0.f, 0.f};
  }
  const f32x4 zero = {0.f, 0.f, 0.f, 0.f};

  for (int si = 0; si < 16; ++si) {
    const int sc = (si + scoff) & 15;
    const int ffb = wv * 512 + sc * 32;
    f16x8 wf0 = *(const f16x8*)(w1h + (ffb + nl) * 32 + g * 8);
    f16x8 wf1 = *(const f16x8*)(w1h + (ffb + 16 + nl) * 32 + g * 8);
    float4 bv0 = *(const float4*)(b1 + ffb + g4);
    float4 bv1 = *(const float4*)(b1 + ffb + 16 + g4);
    const _Float16* cb = w2h + (ffb >> 5) * 1024;
    f16x4 a0lo = *(const f16x4*)(cb + nl * 32 + g4);
    f16x4 a0hi = *(const f16x4*)(cb + nl * 32 + 16 + g4);
    f16x4 a1lo = *(const f16x4*)(cb + (16 + nl) * 32 + g4);
    f16x4 a1hi = *(const f16x4*)(cb + (16 + nl) * 32 + 16 + g4);
    f16x8 A0, A1;
    #pragma unroll
    for (int j = 0; j < 4; ++j) {
      A0[j] = a0lo[j]; A0[4 + j] = a0hi[j];
      A1[j] = a1lo[j]; A1[4 + j] = a1hi[j];
    }
    #pragma unroll
    for (int tt = 0; tt < 3; ++tt) {
      f32x4 cc0 = __builtin_amdgcn_mfma_f32_16x16x32_f16(wf0, hfrag[tt], zero, 0, 0, 0);
      f32x4 cc1 = __builtin_amdgcn_mfma_f32_16x16x32_f16(wf1, hfrag[tt], zero, 0, 0, 0);
      f16x8 uB;
      uB[0] = (_Float16)fmaxf(cc0[0] + bv0.x, 0.f);
      uB[1] = (_Float16)fmaxf(cc0[1] + bv0.y, 0.f);
      uB[2] = (_Float16)fmaxf(cc0[2] + bv0.z, 0.f);
      uB[3] = (_Float16)fmaxf(cc0[3] + bv0.w, 0.f);
      uB[4] = (_Float16)fmaxf(cc1[0] + bv1.x, 0.f);
      uB[5] = (_Float16)fmaxf(cc1[1] + bv1.y, 0.f);
      uB[6] = (_Float16)fmaxf(cc1[2] + bv1.z, 0.f);
      uB[7] = (_Float16)fmaxf(cc1[3] + bv1.w, 0.f);
      acc0[tt] = __builtin_amdgcn_mfma_f32_16x16x32_f16(A0, uB, acc0[tt], 0, 0, 0);
      acc1[tt] = __builtin_amdgcn_mfma_f32_16x16x32_f16(A1, uB, acc1[tt], 0, 0, 0);
    }
  }
  #pragma unroll
  for (int tt = 0; tt < 3; ++tt) {
    #pragma unroll
    for (int r = 0; r < 4; ++r) {
      yw[wv][(tt * 16 + nl) * 33 + g4 + r]      = acc0[tt][r];
      yw[wv][(tt * 16 + nl) * 33 + 16 + g4 + r] = acc1[tt][r];
    }
  }
  __syncthreads();

  // reduce 4 wave partials + b2 + residual(h1) -> pre_s
  {
    int idx = t;
    #pragma unroll
    for (int u = 0; u < 6; ++u, idx += 256) {
      int tok = idx >> 5, d = idx & 31;
      int off = tok * 33 + d;
      float v = yw[0][off] + yw[1][off] + yw[2][off] + yw[3][off]
              + b2[d] + h1[off];
      pre_s[off] = v;
    }
  }
  __syncthreads();

  if (t < FTOK) {
    float mu = 0.f;
    #pragma unroll
    for (int d = 0; d < 32; ++d) mu += pre_s[t * 33 + d];
    mu *= (1.f / 32.f);
    float var = 0.f;
    #pragma unroll
    for (int d = 0; d < 32; ++d) { float dv = pre_s[t * 33 + d] - mu; var += dv * dv; }
    float rs = rsqrtf(var * (1.f / 32.f) + 1e-5f);
    const int rr = r0 + t;
    float* hrow = (float*)h + (size_t)rr * 32;
    float hn[32];
    #pragma unroll
    for (int d = 0; d < 32; ++d) {
      hn[d] = (pre_s[t * 33 + d] - mu) * rs * lw[d] + lb[d];
      hrow[d] = hn[d];
    }
    if (do_head && t > 0) {
      float a = ob[0];
      #pragma unroll
      for (int d = 0; d < 32; ++d) a += hn[d] * ow[d];
      sv1[t - 1] = fmaxf(a, 0.f);
    }
  }

  // ---- fused head MLP for the block's batch element (L=1 only) ----
  if (do_head) {
    __syncthreads();
    const int l = blockIdx.x;
    {
      float a = m0b[t];
      const float* wr = m0w + t * NS;
      #pragma unroll
      for (int s = 0; s < NS; ++s) a += sv1[s] * wr[s];
      hid[t] = fmaxf(a, 0.f);
    }
    __syncthreads();
    {
      float a = m1b[t];
      const float4* wr = (const float4*)(m1w + t * NHID);
      #pragma unroll 8
      for (int j4 = 0; j4 < 64; ++j4) {
        float4 w = wr[j4];
        a += hid[4 * j4 + 0] * w.x + hid[4 * j4 + 1] * w.y
           + hid[4 * j4 + 2] * w.z + hid[4 * j4 + 3] * w.w;
      }
      float h2 = fmaxf(a, 0.f);
      float part = h2 * m2w[t];
      #pragma unroll
      for (int off = 32; off > 0; off >>= 1) part += __shfl_down(part, off, 64);
      if ((t & 63) == 0) red[t >> 6] = part;
    }
    __syncthreads();
    if (t == 0) out[l] = fmaxf(red[0] + red[1] + red[2] + red[3] + m2b[0], 0.f);
  }
}

extern "C" void kernel_launch(void* const* d_in, const int* in_sizes, int n_in,
                              void* d_out, int out_size, void* d_ws, size_t ws_size,
                              hipStream_t stream) {
  (void)in_sizes; (void)n_in; (void)out_size; (void)ws_size;
  const float* x     = (const float*)d_in[0];
  const float* w_in  = (const float*)d_in[1];
  const float* b_in  = (const float*)d_in[2];
  const float* w_pos = (const float*)d_in[3];
  const float* b_pos = (const float*)d_in[4];
  const float* cls   = (const float*)d_in[5];
  const float* wi    = (const float*)d_in[6];
  const float* bi    = (const float*)d_in[7];
  const float* wo    = (const float*)d_in[8];
  const float* bo    = (const float*)d_in[9];
  const float* l1w   = (const float*)d_in[10];
  const float* l1b   = (const float*)d_in[11];
  const float* f1w   = (const float*)d_in[12];
  const float* f1b   = (const float*)d_in[13];
  const float* f2w   = (const float*)d_in[14];
  const float* f2b   = (const float*)d_in[15];
  const float* l2w   = (const float*)d_in[16];
  const float* l2b   = (const float*)d_in[17];
  const float* ow    = (const float*)d_in[18];
  const float* ob    = (const float*)d_in[19];
  const float* m0w   = (const float*)d_in[20];
  const float* m0b   = (const float*)d_in[21];
  const float* m1w   = (const float*)d_in[22];
  const float* m1b   = (const float*)d_in[23];
  const float* m2w   = (const float*)d_in[24];
  const float* m2b   = (const float*)d_in[25];
  float* out = (float*)d_out;

  float* ws   = (float*)d_ws;
  float* h    = ws;                           // [0, 786432)
  float* o    = ws + 786432;                  // [786432, 1572864)
  float* R2   = ws + 1572864;                 // [1572864, 2752512)
  _Float16* Kp = (_Float16*)R2;
  _Float16* Vt = (_Float16*)(R2 + 786432);
  _Float16* w1h = (_Float16*)(ws + 2776576);  // 65536 f32 slots
  _Float16* w2h = (_Float16*)(ws + 2842112);  // 65536 f32 slots -> end 2907648

  prep_embed_kernel<<<3584, 256, 0, stream>>>(f1w, f2w, w1h, w2h,
                                              x, w_in, b_in, w_pos, b_pos, cls, h);
  for (int L = 0; L < 2; ++L) {
    kv_kernel<<<384, 256, 0, stream>>>(h, wi + L * 3072, bi + L * 96, Kp, Vt);
    attn_mfma_kernel<<<768, 256, 0, stream>>>(h, wi + L * 3072, bi + L * 96, Kp, Vt, o);
    ff_fused_kernel<<<512, 256, 0, stream>>>(h, o, wo + L * 1024, bo + L * 32,
                                             l1w + L * 32, l1b + L * 32,
                                             w1h + L * 65536, f1b + L * NFF,
                                             w2h + L * 65536, f2b + L * 32,
                                             l2w + L * 32, l2b + L * 32,
                                             ow, ob, m0w, m0b, m1w, m1b, m2w, m2b,
                                             out, L);
  }
}